// Round 1
// baseline (660.939 us; speedup 1.0000x reference)
//
#include <hip/hip_runtime.h>

typedef unsigned long long ull;

#define BB 2
#define QQ 300
#define CC 80
#define KK 100
#define HM 200
#define WM 200

// ---------------------------------------------------------------------------
// Kernel A: per-batch top-100 of sigmoid(class_logits).flatten() via radix
// select on float bits (all positive -> uint order == float order), exact
// JAX tie-break (value desc, index asc). Also writes labels + clipped boxes,
// and zeroes the per-query accumulators in ws.
// ---------------------------------------------------------------------------
__global__ __launch_bounds__(256) void mdh_topk_kernel(
    const float* __restrict__ cls,
    const float* __restrict__ boxes,
    const int* __restrict__ hptr,
    const int* __restrict__ wptr,
    float* __restrict__ out,
    float* __restrict__ ws_val,
    int* __restrict__ ws_qidx,
    float* __restrict__ ws_area,
    ull* __restrict__ acc_sig,
    unsigned int* __restrict__ acc_cnt)
{
    const int b = blockIdx.x;
    const int tid = threadIdx.x;
    const int N = QQ * CC;
    const float* lg = cls + (size_t)b * N;

    __shared__ int hist[256];
    __shared__ unsigned int sh_prefix;
    __shared__ int sh_krem;
    __shared__ int cntG, cntE;
    __shared__ float gV[128];
    __shared__ int gI[128];
    __shared__ int eI[256];
    __shared__ int fIdx[KK];
    __shared__ float fVal[KK];

    // zero accumulators for this batch (ws is poisoned 0xAA, not re-poisoned)
    for (int t = tid; t < KK; t += blockDim.x) {
        acc_sig[b * KK + t] = 0ull;
        acc_cnt[b * KK + t] = 0u;
    }

    unsigned int prefix = 0u;
    int krem = KK;
    for (int round = 0; round < 4; ++round) {
        const int shift = 24 - 8 * round;
        const unsigned int hmask = (round == 0) ? 0u : (0xFFFFFFFFu << (shift + 8));
        for (int t = tid; t < 256; t += blockDim.x) hist[t] = 0;
        __syncthreads();
        for (int i = tid; i < N; i += blockDim.x) {
            float s = 1.0f / (1.0f + expf(-lg[i]));
            unsigned int key = __float_as_uint(s);
            if ((key & hmask) == (prefix & hmask))
                atomicAdd(&hist[(key >> shift) & 255], 1);
        }
        __syncthreads();
        if (tid == 0) {
            int acc = 0, sel = 0;
            for (int bin = 255; bin >= 0; --bin) {
                int c = hist[bin];
                if (acc + c >= krem) { sel = bin; break; }
                acc += c;
            }
            sh_prefix = prefix | ((unsigned int)sel << shift);
            sh_krem = krem - acc;
        }
        __syncthreads();
        prefix = sh_prefix;
        krem = sh_krem;
        __syncthreads();
    }

    const unsigned int T = prefix;   // exact key of the 100th-largest
    if (tid == 0) { cntG = 0; cntE = 0; }
    __syncthreads();
    for (int i = tid; i < N; i += blockDim.x) {
        float s = 1.0f / (1.0f + expf(-lg[i]));
        unsigned int key = __float_as_uint(s);
        if (key > T) {
            int p = atomicAdd(&cntG, 1);
            if (p < 128) { gV[p] = s; gI[p] = i; }
        } else if (key == T) {
            int p = atomicAdd(&cntE, 1);
            if (p < 256) eI[p] = i;
        }
    }
    __syncthreads();
    const int nG = min(cntG, 128);   // == 100 - krem by construction
    const int nE = min(cntE, 256);

    if (tid < nG) {
        float v = gV[tid]; int idx = gI[tid];
        int r = 0;
        for (int j = 0; j < nG; ++j) {
            float vj = gV[j]; int ij = gI[j];
            if (vj > v || (vj == v && ij < idx)) ++r;
        }
        if (r < KK) { fIdx[r] = idx; fVal[r] = v; }
    }
    if (tid < nE) {
        int idx = eI[tid];
        int r = 0;
        for (int j = 0; j < nE; ++j) if (eI[j] < idx) ++r;
        if (r < krem && (nG + r) < KK) { fIdx[nG + r] = idx; fVal[nG + r] = __uint_as_float(T); }
    }
    __syncthreads();

    const int h = *hptr, w = *wptr;
    const float fw = (float)w, fh = (float)h;
    if (tid < KK) {
        int idx = fIdx[tid];
        float val = fVal[tid];
        int q = idx / CC;
        int label = idx - q * CC;
        int o = b * KK + tid;
        out[BB * KK * 5 + o] = (float)label;               // labels chunk
        const float* bx = boxes + ((size_t)(b * QQ + q)) * 4;
        float cx = bx[0], cy = bx[1], bw = bx[2], bh = bx[3];
        float x1 = fminf(fmaxf((cx - bw * 0.5f) * fw, 0.0f), fw - 1.0f);
        float y1 = fminf(fmaxf((cy - bh * 0.5f) * fh, 0.0f), fh - 1.0f);
        float x2 = fminf(fmaxf((cx + bw * 0.5f) * fw, 0.0f), fw - 1.0f);
        float y2 = fminf(fmaxf((cy + bh * 0.5f) * fh, 0.0f), fh - 1.0f);
        float* br = out + (size_t)o * 5;
        br[0] = x1; br[1] = y1; br[2] = x2; br[3] = y2;    // boxes_scores[:,0:4]
        ws_val[o] = val;
        ws_qidx[o] = q;
        ws_area[o] = (x2 - x1) * (y2 - y1);
    }
}

// ---------------------------------------------------------------------------
// Kernel B: bilinear x4 upsample of the selected 200x200 logits, write binary
// mask (0/1 float), accumulate per-query sigmoid-sum (fixed point, exact
// deterministic) and positive-pixel count.
// Grid: (ceil(h*w/1024), B*K). Each thread: 4 consecutive pixels (float4 out).
// ---------------------------------------------------------------------------
__global__ __launch_bounds__(256) void mdh_masks_kernel(
    const float* __restrict__ mp,
    const int* __restrict__ ws_qidx,
    const int* __restrict__ hptr,
    const int* __restrict__ wptr,
    float* __restrict__ out_masks,
    ull* __restrict__ acc_sig,
    unsigned int* __restrict__ acc_cnt)
{
    const int bq = blockIdx.y;
    const int b = bq / KK;
    const int q = ws_qidx[bq];
    const int h = *hptr, w = *wptr;
    const long long pix = (long long)h * w;
    const float* __restrict__ src = mp + ((size_t)(b * QQ + q)) * (HM * WM);
    const float sy = (float)HM / (float)h;
    const float sx = (float)WM / (float)w;

    const long long p0 = (long long)blockIdx.x * 1024 + (long long)threadIdx.x * 4;
    float ssum = 0.0f;
    int scnt = 0;
    if (p0 < pix) {
        int y = (int)(p0 / w);
        int x = (int)(p0 - (long long)y * w);
        float pmv[4];
        const bool fast = (w == 4 * WM) && ((x & 3) == 0) && (p0 + 3 < pix);
        if (fast) {
            // exact quarter-pixel weights: x = 4k + r uses cols k-1,k,k+1
            float yi = ((float)y + 0.5f) * sy - 0.5f;
            float rf = floorf(yi);
            float fy = yi - rf;                 // exact {0.625,0.875,0.125,0.375}
            int r0 = max((int)rf, 0);
            int r1 = min((int)rf + 1, HM - 1);
            int k = x >> 2;
            int cm1 = max(k - 1, 0);
            int cp1 = min(k + 1, WM - 1);
            const float* row0 = src + r0 * WM;
            const float* row1 = src + r1 * WM;
            float am1 = row0[cm1], a0 = row0[k], ap1 = row0[cp1];
            float bm1 = row1[cm1], b0 = row1[k], bp1 = row1[cp1];
            float wy0 = 1.0f - fy;
            float vm1 = wy0 * am1 + fy * bm1;
            float v0  = wy0 * a0  + fy * b0;
            float vp1 = wy0 * ap1 + fy * bp1;
            pmv[0] = 0.375f * vm1 + 0.625f * v0;
            pmv[1] = 0.125f * vm1 + 0.875f * v0;
            pmv[2] = 0.875f * v0 + 0.125f * vp1;
            pmv[3] = 0.625f * v0 + 0.375f * vp1;
        } else {
            for (int j = 0; j < 4; ++j) {
                long long p = p0 + j;
                if (p >= pix) { pmv[j] = -1.0f; continue; }
                int yy = (int)(p / w);
                int xx = (int)(p - (long long)yy * w);
                float yi = ((float)yy + 0.5f) * sy - 0.5f;
                float rf = floorf(yi); float fy = yi - rf;
                int r0 = max((int)rf, 0); int r1 = min((int)rf + 1, HM - 1);
                float xi = ((float)xx + 0.5f) * sx - 0.5f;
                float cf = floorf(xi); float fx = xi - cf;
                int c0 = max((int)cf, 0); int c1 = min((int)cf + 1, WM - 1);
                float a  = src[r0 * WM + c0], b2 = src[r0 * WM + c1];
                float c  = src[r1 * WM + c0], d2 = src[r1 * WM + c1];
                float t0 = (1.0f - fy) * a  + fy * c;
                float t1 = (1.0f - fy) * b2 + fy * d2;
                pmv[j] = (1.0f - fx) * t0 + fx * t1;
            }
        }
        float4 ov;
        float* ovp = &ov.x;
        #pragma unroll
        for (int j = 0; j < 4; ++j) {
            bool m = pmv[j] > 0.0f;
            ovp[j] = m ? 1.0f : 0.0f;
            if (m) { ssum += 1.0f / (1.0f + __expf(-pmv[j])); scnt++; }
        }
        if (fast) {
            *(float4*)(out_masks + (size_t)bq * pix + p0) = ov;
        } else {
            for (int j = 0; j < 4; ++j) {
                long long p = p0 + j;
                if (p < pix) out_masks[(size_t)bq * pix + p] = ovp[j];
            }
        }
    }

    // deterministic block reduction (fixed order), one atomic per block
    for (int off = 32; off > 0; off >>= 1) {
        ssum += __shfl_down(ssum, off);
        scnt += __shfl_down(scnt, off);
    }
    __shared__ float wsum[4];
    __shared__ int wcnt[4];
    const int wid = threadIdx.x >> 6;
    const int lane = threadIdx.x & 63;
    if (lane == 0) { wsum[wid] = ssum; wcnt[wid] = scnt; }
    __syncthreads();
    if (threadIdx.x == 0) {
        float t = wsum[0] + wsum[1] + wsum[2] + wsum[3];
        int c = wcnt[0] + wcnt[1] + wcnt[2] + wcnt[3];
        if (c > 0) {
            // fixed-point 2^32 accumulate -> bit-deterministic across replays
            atomicAdd(&acc_sig[bq], (ull)((double)t * 4294967296.0 + 0.5));
            atomicAdd(&acc_cnt[bq], (unsigned int)c);
        }
    }
}

// ---------------------------------------------------------------------------
// Kernel C: obj = sig_sum / (count + 1e-6); pred_score; keep flags; write
// boxes_scores[:,4] and keep chunk.
// ---------------------------------------------------------------------------
__global__ void mdh_final_kernel(
    const ull* __restrict__ acc_sig,
    const unsigned int* __restrict__ acc_cnt,
    const float* __restrict__ ws_val,
    const float* __restrict__ ws_area,
    float* __restrict__ out,
    long long pix)
{
    int t = blockIdx.x * blockDim.x + threadIdx.x;
    if (t < BB * KK) {
        float sig = (float)((double)acc_sig[t] * (1.0 / 4294967296.0));
        unsigned int cnt = acc_cnt[t];
        float obj = sig / ((float)cnt + 1e-6f);
        float ps = ws_val[t] * obj;
        out[(size_t)t * 5 + 4] = ps;
        bool keep = (cnt > 5) && (ws_area[t] > 10.0f) && (ps > 0.05f);
        out[(size_t)(BB * KK * 5 + BB * KK) + (size_t)BB * KK * pix + t] = keep ? 1.0f : 0.0f;
    }
}

extern "C" void kernel_launch(void* const* d_in, const int* in_sizes, int n_in,
                              void* d_out, int out_size, void* d_ws, size_t ws_size,
                              hipStream_t stream)
{
    const float* mp    = (const float*)d_in[0];   // (B,Q,200,200) f32
    const float* cls   = (const float*)d_in[1];   // (B,Q,80) f32
    const float* boxes = (const float*)d_in[2];   // (B,Q,4) f32
    const int* hptr    = (const int*)d_in[3];     // scalar h
    const int* wptr    = (const int*)d_in[4];     // scalar w
    float* out = (float*)d_out;

    // out layout: boxes_scores (B*K*5) | labels (B*K) | masks (B*K*h*w) | keep (B*K)
    const long long pix = ((long long)out_size - (long long)BB * KK * 7) / ((long long)BB * KK);

    char* wsb = (char*)d_ws;
    ull* acc_sig          = (ull*)wsb;                                   // 200*8
    unsigned int* acc_cnt = (unsigned int*)(wsb + 200 * 8);              // 200*4
    float* ws_val         = (float*)(wsb + 200 * 8 + 200 * 4);           // 200*4
    int* ws_qidx          = (int*)(wsb + 200 * 8 + 200 * 8);             // 200*4
    float* ws_area        = (float*)(wsb + 200 * 8 + 200 * 8 + 200 * 4); // 200*4

    mdh_topk_kernel<<<BB, 256, 0, stream>>>(cls, boxes, hptr, wptr, out,
                                            ws_val, ws_qidx, ws_area, acc_sig, acc_cnt);

    const int nblk = (int)((pix + 1023) / 1024);
    mdh_masks_kernel<<<dim3(nblk, BB * KK), 256, 0, stream>>>(
        mp, ws_qidx, hptr, wptr, out + BB * KK * 6, acc_sig, acc_cnt);

    mdh_final_kernel<<<1, 256, 0, stream>>>(acc_sig, acc_cnt, ws_val, ws_area, out, pix);
}

// Round 2
// 266.249 us; speedup vs baseline: 2.4824x; 2.4824x over previous
//
#include <hip/hip_runtime.h>

typedef unsigned long long ull;

#define BB 2
#define QQ 300
#define CC 80
#define KK 100
#define HM 200
#define WM 200

// ---------------------------------------------------------------------------
// Kernel A0: compute sigmoid keys (float bits; all positive -> uint order ==
// float order) for all B*Q*C class logits; zero the per-query accumulators.
// ---------------------------------------------------------------------------
__global__ __launch_bounds__(256) void mdh_keys_kernel(
    const float* __restrict__ cls,
    unsigned int* __restrict__ keys,
    ull* __restrict__ acc_sig,
    unsigned int* __restrict__ acc_cnt)
{
    int i = blockIdx.x * 256 + threadIdx.x;
    if (i < BB * QQ * CC) {
        float s = 1.0f / (1.0f + expf(-cls[i]));
        keys[i] = __float_as_uint(s);
    }
    if (i < BB * KK) {
        acc_sig[i] = 0ull;
        acc_cnt[i] = 0u;
    }
}

// ---------------------------------------------------------------------------
// Kernel A: per-batch top-100 via 3-round radix select (11/11/10 bits) on the
// precomputed keys, exact JAX tie-break (value desc, index asc). Writes
// labels + clipped boxes + per-query metadata.
// ---------------------------------------------------------------------------
__global__ __launch_bounds__(256) void mdh_topk_kernel(
    const unsigned int* __restrict__ keys_all,
    const float* __restrict__ boxes,
    const int* __restrict__ hptr,
    const int* __restrict__ wptr,
    float* __restrict__ out,
    float* __restrict__ ws_val,
    int* __restrict__ ws_qidx,
    float* __restrict__ ws_area)
{
    const int b = blockIdx.x;
    const int tid = threadIdx.x;
    const int N = QQ * CC;   // 24000, divisible by 4
    const unsigned int* __restrict__ keys = keys_all + (size_t)b * N;

    __shared__ int hist[2048];
    __shared__ int chunkSum[256];
    __shared__ unsigned int sh_prefix;
    __shared__ int sh_krem;
    __shared__ int cntG, cntE;
    __shared__ float gV[128];
    __shared__ int gI[128];
    __shared__ int eI[256];
    __shared__ int fIdx[KK];
    __shared__ float fVal[KK];

    unsigned int prefix = 0u;
    int krem = KK;

    #pragma unroll
    for (int round = 0; round < 3; ++round) {
        const int shift = (round == 0) ? 21 : (round == 1) ? 10 : 0;
        const int nbits = (round == 2) ? 10 : 11;
        const unsigned int binmask = (1u << nbits) - 1u;
        // hmask: high bits that must match current prefix
        const unsigned int hmask = (round == 0) ? 0u : (0xFFFFFFFFu << (shift + nbits));

        for (int t = tid; t < 2048; t += 256) hist[t] = 0;
        __syncthreads();

        for (int i = tid * 4; i < N; i += 1024) {
            uint4 kv = *(const uint4*)(keys + i);
            unsigned int ka[4] = {kv.x, kv.y, kv.z, kv.w};
            #pragma unroll
            for (int j = 0; j < 4; ++j) {
                if ((ka[j] & hmask) == (prefix & hmask))
                    atomicAdd(&hist[(ka[j] >> shift) & binmask], 1);
            }
        }
        __syncthreads();

        // two-level descending scan to find the bin holding the krem-th item
        int cs = 0;
        #pragma unroll
        for (int j = 0; j < 8; ++j) cs += hist[tid * 8 + j];
        chunkSum[tid] = cs;
        __syncthreads();
        if (tid == 0) {
            int acc = 0, sel = 0, kr = krem;
            for (int c = 255; c >= 0; --c) {
                if (acc + chunkSum[c] >= kr) {
                    for (int bin = c * 8 + 7; bin >= c * 8; --bin) {
                        int h2 = hist[bin];
                        if (acc + h2 >= kr) { sel = bin; break; }
                        acc += h2;
                    }
                    break;
                }
                acc += chunkSum[c];
            }
            sh_prefix = prefix | ((unsigned int)sel << shift);
            sh_krem = krem - acc;
        }
        __syncthreads();
        prefix = sh_prefix;
        krem = sh_krem;
        __syncthreads();
    }

    const unsigned int T = prefix;   // exact key of the 100th-largest
    if (tid == 0) { cntG = 0; cntE = 0; }
    __syncthreads();
    for (int i = tid * 4; i < N; i += 1024) {
        uint4 kv = *(const uint4*)(keys + i);
        unsigned int ka[4] = {kv.x, kv.y, kv.z, kv.w};
        #pragma unroll
        for (int j = 0; j < 4; ++j) {
            unsigned int key = ka[j];
            if (key > T) {
                int p = atomicAdd(&cntG, 1);
                if (p < 128) { gV[p] = __uint_as_float(key); gI[p] = i + j; }
            } else if (key == T) {
                int p = atomicAdd(&cntE, 1);
                if (p < 256) eI[p] = i + j;
            }
        }
    }
    __syncthreads();
    const int nG = min(cntG, 128);   // == 100 - krem by construction (<=99)
    const int nE = min(cntE, 256);

    if (tid < nG) {
        float v = gV[tid]; int idx = gI[tid];
        int r = 0;
        for (int j = 0; j < nG; ++j) {
            float vj = gV[j]; int ij = gI[j];
            if (vj > v || (vj == v && ij < idx)) ++r;
        }
        if (r < KK) { fIdx[r] = idx; fVal[r] = v; }
    }
    if (tid < nE) {
        int idx = eI[tid];
        int r = 0;
        for (int j = 0; j < nE; ++j) if (eI[j] < idx) ++r;
        if (r < krem && (nG + r) < KK) { fIdx[nG + r] = idx; fVal[nG + r] = __uint_as_float(T); }
    }
    __syncthreads();

    const int h = *hptr, w = *wptr;
    const float fw = (float)w, fh = (float)h;
    if (tid < KK) {
        int idx = fIdx[tid];
        float val = fVal[tid];
        int q = idx / CC;
        int label = idx - q * CC;
        int o = b * KK + tid;
        out[BB * KK * 5 + o] = (float)label;               // labels chunk
        const float* bx = boxes + ((size_t)(b * QQ + q)) * 4;
        float cx = bx[0], cy = bx[1], bw = bx[2], bh = bx[3];
        float x1 = fminf(fmaxf((cx - bw * 0.5f) * fw, 0.0f), fw - 1.0f);
        float y1 = fminf(fmaxf((cy - bh * 0.5f) * fh, 0.0f), fh - 1.0f);
        float x2 = fminf(fmaxf((cx + bw * 0.5f) * fw, 0.0f), fw - 1.0f);
        float y2 = fminf(fmaxf((cy + bh * 0.5f) * fh, 0.0f), fh - 1.0f);
        float* br = out + (size_t)o * 5;
        br[0] = x1; br[1] = y1; br[2] = x2; br[3] = y2;    // boxes_scores[:,0:4]
        ws_val[o] = val;
        ws_qidx[o] = q;
        ws_area[o] = (x2 - x1) * (y2 - y1);
    }
}

// ---------------------------------------------------------------------------
// Kernel B (specialized h=w=800): each thread computes a 4x4 output tile from
// a 3x3 source neighborhood with compile-time weights. 16 px/thread, 4 float4
// stores, no runtime divisions. Same arithmetic expressions as the validated
// generic fast path.
// Grid: (ceil(40000/256)=157, B*K).
// ---------------------------------------------------------------------------
__global__ __launch_bounds__(256) void mdh_masks800_kernel(
    const float* __restrict__ mp,
    const int* __restrict__ ws_qidx,
    float* __restrict__ out_masks,
    ull* __restrict__ acc_sig,
    unsigned int* __restrict__ acc_cnt)
{
    const int bq = blockIdx.y;
    const int b = bq / KK;
    const int q = ws_qidx[bq];
    const float* __restrict__ src = mp + ((size_t)(b * QQ + q)) * (HM * WM);

    const int t = blockIdx.x * 256 + threadIdx.x;
    float ssum = 0.0f;
    int scnt = 0;

    if (t < HM * WM) {
        const int m = t / WM;          // div by constant -> mul_hi
        const int k = t - m * WM;
        const int rm1 = (m > 0 ? m - 1 : 0) * WM;
        const int r0  = m * WM;
        const int rp1 = (m < HM - 1 ? m + 1 : HM - 1) * WM;
        const int cm1 = (k > 0 ? k - 1 : 0);
        const int cp1 = (k < WM - 1 ? k + 1 : WM - 1);

        float a0m = src[rm1 + cm1], a00 = src[rm1 + k], a0p = src[rm1 + cp1];
        float a1m = src[r0  + cm1], a10 = src[r0  + k], a1p = src[r0  + cp1];
        float a2m = src[rp1 + cm1], a20 = src[rp1 + k], a2p = src[rp1 + cp1];

        float* dst = out_masks + (size_t)bq * 640000 + (size_t)(4 * m) * 800 + 4 * k;

        #pragma unroll
        for (int r = 0; r < 4; ++r) {
            float um, u0, up;
            if (r == 0)      { um = 0.375f*a0m + 0.625f*a1m; u0 = 0.375f*a00 + 0.625f*a10; up = 0.375f*a0p + 0.625f*a1p; }
            else if (r == 1) { um = 0.125f*a0m + 0.875f*a1m; u0 = 0.125f*a00 + 0.875f*a10; up = 0.125f*a0p + 0.875f*a1p; }
            else if (r == 2) { um = 0.875f*a1m + 0.125f*a2m; u0 = 0.875f*a10 + 0.125f*a20; up = 0.875f*a1p + 0.125f*a2p; }
            else             { um = 0.625f*a1m + 0.375f*a2m; u0 = 0.625f*a10 + 0.375f*a20; up = 0.625f*a1p + 0.375f*a2p; }

            float pmv[4];
            pmv[0] = 0.375f * um + 0.625f * u0;
            pmv[1] = 0.125f * um + 0.875f * u0;
            pmv[2] = 0.875f * u0 + 0.125f * up;
            pmv[3] = 0.625f * u0 + 0.375f * up;

            float4 ov;
            float* ovp = &ov.x;
            #pragma unroll
            for (int j = 0; j < 4; ++j) {
                bool pos = pmv[j] > 0.0f;
                ovp[j] = pos ? 1.0f : 0.0f;
                if (pos) { ssum += 1.0f / (1.0f + __expf(-pmv[j])); scnt++; }
            }
            *(float4*)(dst + r * 800) = ov;
        }
    }

    // deterministic block reduction (fixed order), one atomic pair per block
    for (int off = 32; off > 0; off >>= 1) {
        ssum += __shfl_down(ssum, off);
        scnt += __shfl_down(scnt, off);
    }
    __shared__ float wsum[4];
    __shared__ int wcnt[4];
    const int wid = threadIdx.x >> 6;
    const int lane = threadIdx.x & 63;
    if (lane == 0) { wsum[wid] = ssum; wcnt[wid] = scnt; }
    __syncthreads();
    if (threadIdx.x == 0) {
        float tt = wsum[0] + wsum[1] + wsum[2] + wsum[3];
        int c = wcnt[0] + wcnt[1] + wcnt[2] + wcnt[3];
        if (c > 0) {
            atomicAdd(&acc_sig[bq], (ull)((double)tt * 4294967296.0 + 0.5));
            atomicAdd(&acc_cnt[bq], (unsigned int)c);
        }
    }
}

// ---------------------------------------------------------------------------
// Kernel B-generic: fallback for pix != 640000 (unused for this problem).
// ---------------------------------------------------------------------------
__global__ __launch_bounds__(256) void mdh_masks_kernel(
    const float* __restrict__ mp,
    const int* __restrict__ ws_qidx,
    const int* __restrict__ hptr,
    const int* __restrict__ wptr,
    float* __restrict__ out_masks,
    ull* __restrict__ acc_sig,
    unsigned int* __restrict__ acc_cnt)
{
    const int bq = blockIdx.y;
    const int b = bq / KK;
    const int q = ws_qidx[bq];
    const int h = *hptr, w = *wptr;
    const long long pix = (long long)h * w;
    const float* __restrict__ src = mp + ((size_t)(b * QQ + q)) * (HM * WM);
    const float sy = (float)HM / (float)h;
    const float sx = (float)WM / (float)w;

    const long long p0 = (long long)blockIdx.x * 1024 + (long long)threadIdx.x * 4;
    float ssum = 0.0f;
    int scnt = 0;
    if (p0 < pix) {
        float pmv[4];
        for (int j = 0; j < 4; ++j) {
            long long p = p0 + j;
            if (p >= pix) { pmv[j] = -1.0f; continue; }
            int yy = (int)(p / w);
            int xx = (int)(p - (long long)yy * w);
            float yi = ((float)yy + 0.5f) * sy - 0.5f;
            float rf = floorf(yi); float fy = yi - rf;
            int r0 = max((int)rf, 0); int r1 = min((int)rf + 1, HM - 1);
            float xi = ((float)xx + 0.5f) * sx - 0.5f;
            float cf = floorf(xi); float fx = xi - cf;
            int c0 = max((int)cf, 0); int c1 = min((int)cf + 1, WM - 1);
            float a  = src[r0 * WM + c0], b2 = src[r0 * WM + c1];
            float c  = src[r1 * WM + c0], d2 = src[r1 * WM + c1];
            float t0 = (1.0f - fy) * a  + fy * c;
            float t1 = (1.0f - fy) * b2 + fy * d2;
            pmv[j] = (1.0f - fx) * t0 + fx * t1;
        }
        for (int j = 0; j < 4; ++j) {
            long long p = p0 + j;
            if (p >= pix) continue;
            bool pos = pmv[j] > 0.0f;
            out_masks[(size_t)bq * pix + p] = pos ? 1.0f : 0.0f;
            if (pos) { ssum += 1.0f / (1.0f + __expf(-pmv[j])); scnt++; }
        }
    }

    for (int off = 32; off > 0; off >>= 1) {
        ssum += __shfl_down(ssum, off);
        scnt += __shfl_down(scnt, off);
    }
    __shared__ float wsum[4];
    __shared__ int wcnt[4];
    const int wid = threadIdx.x >> 6;
    const int lane = threadIdx.x & 63;
    if (lane == 0) { wsum[wid] = ssum; wcnt[wid] = scnt; }
    __syncthreads();
    if (threadIdx.x == 0) {
        float tt = wsum[0] + wsum[1] + wsum[2] + wsum[3];
        int c = wcnt[0] + wcnt[1] + wcnt[2] + wcnt[3];
        if (c > 0) {
            atomicAdd(&acc_sig[bq], (ull)((double)tt * 4294967296.0 + 0.5));
            atomicAdd(&acc_cnt[bq], (unsigned int)c);
        }
    }
}

// ---------------------------------------------------------------------------
// Kernel C: obj = sig_sum / (count + 1e-6); pred_score; keep flags.
// ---------------------------------------------------------------------------
__global__ void mdh_final_kernel(
    const ull* __restrict__ acc_sig,
    const unsigned int* __restrict__ acc_cnt,
    const float* __restrict__ ws_val,
    const float* __restrict__ ws_area,
    float* __restrict__ out,
    long long pix)
{
    int t = blockIdx.x * blockDim.x + threadIdx.x;
    if (t < BB * KK) {
        float sig = (float)((double)acc_sig[t] * (1.0 / 4294967296.0));
        unsigned int cnt = acc_cnt[t];
        float obj = sig / ((float)cnt + 1e-6f);
        float ps = ws_val[t] * obj;
        out[(size_t)t * 5 + 4] = ps;
        bool keep = (cnt > 5) && (ws_area[t] > 10.0f) && (ps > 0.05f);
        out[(size_t)(BB * KK * 5 + BB * KK) + (size_t)BB * KK * pix + t] = keep ? 1.0f : 0.0f;
    }
}

extern "C" void kernel_launch(void* const* d_in, const int* in_sizes, int n_in,
                              void* d_out, int out_size, void* d_ws, size_t ws_size,
                              hipStream_t stream)
{
    const float* mp    = (const float*)d_in[0];   // (B,Q,200,200) f32
    const float* cls   = (const float*)d_in[1];   // (B,Q,80) f32
    const float* boxes = (const float*)d_in[2];   // (B,Q,4) f32
    const int* hptr    = (const int*)d_in[3];     // scalar h
    const int* wptr    = (const int*)d_in[4];     // scalar w
    float* out = (float*)d_out;

    // out layout: boxes_scores (B*K*5) | labels (B*K) | masks (B*K*h*w) | keep (B*K)
    const long long pix = ((long long)out_size - (long long)BB * KK * 7) / ((long long)BB * KK);

    char* wsb = (char*)d_ws;
    ull* acc_sig          = (ull*)wsb;                       // 200*8   @0
    unsigned int* acc_cnt = (unsigned int*)(wsb + 1600);     // 200*4   @1600
    float* ws_val         = (float*)(wsb + 2400);            // 200*4   @2400
    int* ws_qidx          = (int*)(wsb + 3200);              // 200*4   @3200
    float* ws_area        = (float*)(wsb + 4000);            // 200*4   @4000
    unsigned int* ws_keys = (unsigned int*)(wsb + 4800);     // 48000*4 @4800 (16B aligned)

    mdh_keys_kernel<<<(BB * QQ * CC + 255) / 256, 256, 0, stream>>>(
        cls, ws_keys, acc_sig, acc_cnt);

    mdh_topk_kernel<<<BB, 256, 0, stream>>>(ws_keys, boxes, hptr, wptr, out,
                                            ws_val, ws_qidx, ws_area);

    if (pix == 640000) {
        mdh_masks800_kernel<<<dim3((HM * WM + 255) / 256, BB * KK), 256, 0, stream>>>(
            mp, ws_qidx, out + BB * KK * 6, acc_sig, acc_cnt);
    } else {
        const int nblk = (int)((pix + 1023) / 1024);
        mdh_masks_kernel<<<dim3(nblk, BB * KK), 256, 0, stream>>>(
            mp, ws_qidx, hptr, wptr, out + BB * KK * 6, acc_sig, acc_cnt);
    }

    mdh_final_kernel<<<1, 256, 0, stream>>>(acc_sig, acc_cnt, ws_val, ws_area, out, pix);
}

// Round 3
// 159.658 us; speedup vs baseline: 4.1397x; 1.6676x over previous
//
#include <hip/hip_runtime.h>

typedef unsigned long long ull;
typedef float f32x4 __attribute__((ext_vector_type(4)));

#define BB 2
#define QQ 300
#define CC 80
#define KK 100
#define HM 200
#define WM 200

// ---------------------------------------------------------------------------
// Kernel A: per-batch top-100 via 3-round radix select (11/11/10 bits) on
// sigmoid keys (float bits; all positive -> uint order == float order).
// Round 0 computes keys from logits (expf, bit-identical to prior passing
// rounds) and caches them in ws; rounds 1-2 + collect re-read cached keys.
// 1024 threads (16 waves) for latency hiding. Exact JAX tie-break
// (value desc, index asc). Also zeroes per-query accumulators, writes
// labels + clipped boxes + per-query metadata.
// ---------------------------------------------------------------------------
__global__ __launch_bounds__(1024) void mdh_topk_kernel(
    const float* __restrict__ cls,
    unsigned int* __restrict__ keys_ws,
    const float* __restrict__ boxes,
    const int* __restrict__ hptr,
    const int* __restrict__ wptr,
    float* __restrict__ out,
    float* __restrict__ ws_val,
    int* __restrict__ ws_qidx,
    float* __restrict__ ws_area,
    ull* __restrict__ acc_sig,
    unsigned int* __restrict__ acc_cnt)
{
    const int b = blockIdx.x;
    const int tid = threadIdx.x;
    const int N = QQ * CC;   // 24000
    const float* __restrict__ lg = cls + (size_t)b * N;
    unsigned int* __restrict__ keys = keys_ws + (size_t)b * N;

    __shared__ int hist[2048];
    __shared__ int chunkSum[256];
    __shared__ unsigned int sh_prefix;
    __shared__ int sh_krem;
    __shared__ int cntG, cntE;
    __shared__ float gV[128];
    __shared__ int gI[128];
    __shared__ int eI[256];
    __shared__ int fIdx[KK];
    __shared__ float fVal[KK];

    // zero accumulators (ws is poisoned 0xAA once, never re-poisoned)
    if (tid < KK) {
        acc_sig[b * KK + tid] = 0ull;
        acc_cnt[b * KK + tid] = 0u;
    }

    unsigned int prefix = 0u;
    int krem = KK;

    // ---- round 0: compute keys + 11-bit hist ----
    for (int t = tid; t < 2048; t += 1024) hist[t] = 0;
    __syncthreads();
    for (int i = tid; i < N; i += 1024) {
        float s = 1.0f / (1.0f + expf(-lg[i]));
        unsigned int key = __float_as_uint(s);
        keys[i] = key;
        atomicAdd(&hist[key >> 21], 1);
    }
    __syncthreads();
    {
        int cs = 0;
        if (tid < 256) {
            #pragma unroll
            for (int j = 0; j < 8; ++j) cs += hist[tid * 8 + j];
            chunkSum[tid] = cs;
        }
        __syncthreads();
        if (tid == 0) {
            int acc = 0, sel = 0;
            for (int c = 255; c >= 0; --c) {
                if (acc + chunkSum[c] >= krem) {
                    for (int bin = c * 8 + 7; bin >= c * 8; --bin) {
                        int h2 = hist[bin];
                        if (acc + h2 >= krem) { sel = bin; break; }
                        acc += h2;
                    }
                    break;
                }
                acc += chunkSum[c];
            }
            sh_prefix = (unsigned int)sel << 21;
            sh_krem = krem - acc;
        }
        __syncthreads();
        prefix = sh_prefix;
        krem = sh_krem;
        __syncthreads();
    }

    // ---- rounds 1,2 on cached keys ----
    #pragma unroll
    for (int round = 1; round < 3; ++round) {
        const int shift = (round == 1) ? 10 : 0;
        const int nbits = (round == 1) ? 11 : 10;
        const unsigned int binmask = (1u << nbits) - 1u;
        const unsigned int hmask = 0xFFFFFFFFu << (shift + nbits);

        for (int t = tid; t < 2048; t += 1024) hist[t] = 0;
        __syncthreads();
        for (int i = tid * 4; i < N; i += 4096) {
            uint4 kv = *(const uint4*)(keys + i);
            unsigned int ka[4] = {kv.x, kv.y, kv.z, kv.w};
            #pragma unroll
            for (int j = 0; j < 4; ++j) {
                if ((ka[j] & hmask) == (prefix & hmask))
                    atomicAdd(&hist[(ka[j] >> shift) & binmask], 1);
            }
        }
        __syncthreads();
        int cs = 0;
        if (tid < 256) {
            #pragma unroll
            for (int j = 0; j < 8; ++j) cs += hist[tid * 8 + j];
            chunkSum[tid] = cs;
        }
        __syncthreads();
        if (tid == 0) {
            int acc = 0, sel = 0;
            for (int c = 255; c >= 0; --c) {
                if (acc + chunkSum[c] >= krem) {
                    for (int bin = c * 8 + 7; bin >= c * 8; --bin) {
                        int h2 = hist[bin];
                        if (acc + h2 >= krem) { sel = bin; break; }
                        acc += h2;
                    }
                    break;
                }
                acc += chunkSum[c];
            }
            sh_prefix = prefix | ((unsigned int)sel << shift);
            sh_krem = krem - acc;
        }
        __syncthreads();
        prefix = sh_prefix;
        krem = sh_krem;
        __syncthreads();
    }

    // ---- collect: >T (winners) and ==T (tie candidates) ----
    const unsigned int T = prefix;   // exact key of the 100th-largest
    if (tid == 0) { cntG = 0; cntE = 0; }
    __syncthreads();
    for (int i = tid * 4; i < N; i += 4096) {
        uint4 kv = *(const uint4*)(keys + i);
        unsigned int ka[4] = {kv.x, kv.y, kv.z, kv.w};
        #pragma unroll
        for (int j = 0; j < 4; ++j) {
            unsigned int key = ka[j];
            if (key > T) {
                int p = atomicAdd(&cntG, 1);
                if (p < 128) { gV[p] = __uint_as_float(key); gI[p] = i + j; }
            } else if (key == T) {
                int p = atomicAdd(&cntE, 1);
                if (p < 256) eI[p] = i + j;
            }
        }
    }
    __syncthreads();
    const int nG = min(cntG, 128);   // == 100 - krem by construction (<=99)
    const int nE = min(cntE, 256);

    if (tid < nG) {
        float v = gV[tid]; int idx = gI[tid];
        int r = 0;
        for (int j = 0; j < nG; ++j) {
            float vj = gV[j]; int ij = gI[j];
            if (vj > v || (vj == v && ij < idx)) ++r;
        }
        if (r < KK) { fIdx[r] = idx; fVal[r] = v; }
    }
    if (tid < nE) {
        int idx = eI[tid];
        int r = 0;
        for (int j = 0; j < nE; ++j) if (eI[j] < idx) ++r;
        if (r < krem && (nG + r) < KK) { fIdx[nG + r] = idx; fVal[nG + r] = __uint_as_float(T); }
    }
    __syncthreads();

    const int h = *hptr, w = *wptr;
    const float fw = (float)w, fh = (float)h;
    if (tid < KK) {
        int idx = fIdx[tid];
        float val = fVal[tid];
        int q = idx / CC;
        int label = idx - q * CC;
        int o = b * KK + tid;
        out[BB * KK * 5 + o] = (float)label;               // labels chunk
        const float* bx = boxes + ((size_t)(b * QQ + q)) * 4;
        float cx = bx[0], cy = bx[1], bw = bx[2], bh = bx[3];
        float x1 = fminf(fmaxf((cx - bw * 0.5f) * fw, 0.0f), fw - 1.0f);
        float y1 = fminf(fmaxf((cy - bh * 0.5f) * fh, 0.0f), fh - 1.0f);
        float x2 = fminf(fmaxf((cx + bw * 0.5f) * fw, 0.0f), fw - 1.0f);
        float y2 = fminf(fmaxf((cy + bh * 0.5f) * fh, 0.0f), fh - 1.0f);
        float* br = out + (size_t)o * 5;
        br[0] = x1; br[1] = y1; br[2] = x2; br[3] = y2;    // boxes_scores[:,0:4]
        ws_val[o] = val;
        ws_qidx[o] = q;
        ws_area[o] = (x2 - x1) * (y2 - y1);
    }
}

// ---------------------------------------------------------------------------
// Kernel B (specialized h=w=800): each thread computes a 4x4 output tile from
// a 3x3 source neighborhood with compile-time weights. Non-temporal float4
// stores (write-once data bypasses L2, keeps source tiles resident).
// 1D grid with XCD-chunked swizzle: each XCD walks ~25 consecutive bq's so
// its private L2 holds ~1 source tile at a time.
// Grid: 200 * 157 = 31400 blocks (divisible by 8 -> bijective swizzle).
// ---------------------------------------------------------------------------
__global__ __launch_bounds__(256) void mdh_masks800_kernel(
    const float* __restrict__ mp,
    const int* __restrict__ ws_qidx,
    float* __restrict__ out_masks,
    ull* __restrict__ acc_sig,
    unsigned int* __restrict__ acc_cnt)
{
    // XCD-chunked bijective swizzle (31400 % 8 == 0, 31400/8 = 3925)
    const int orig = blockIdx.x;
    const int wg = (orig & 7) * 3925 + (orig >> 3);
    const int bq = wg / 157;              // compile-time const divisor
    const int chunk = wg - bq * 157;

    const int b = bq / KK;
    const int q = ws_qidx[bq];
    const float* __restrict__ src = mp + ((size_t)(b * QQ + q)) * (HM * WM);

    const int t = chunk * 256 + threadIdx.x;
    float ssum = 0.0f;
    int scnt = 0;

    if (t < HM * WM) {
        const int m = t / WM;             // div by constant -> mul_hi
        const int k = t - m * WM;
        const int rm1 = (m > 0 ? m - 1 : 0) * WM;
        const int r0  = m * WM;
        const int rp1 = (m < HM - 1 ? m + 1 : HM - 1) * WM;
        const int cm1 = (k > 0 ? k - 1 : 0);
        const int cp1 = (k < WM - 1 ? k + 1 : WM - 1);

        float a0m = src[rm1 + cm1], a00 = src[rm1 + k], a0p = src[rm1 + cp1];
        float a1m = src[r0  + cm1], a10 = src[r0  + k], a1p = src[r0  + cp1];
        float a2m = src[rp1 + cm1], a20 = src[rp1 + k], a2p = src[rp1 + cp1];

        float* dst = out_masks + (size_t)bq * 640000 + (size_t)(4 * m) * 800 + 4 * k;

        #pragma unroll
        for (int r = 0; r < 4; ++r) {
            float um, u0, up;
            if (r == 0)      { um = 0.375f*a0m + 0.625f*a1m; u0 = 0.375f*a00 + 0.625f*a10; up = 0.375f*a0p + 0.625f*a1p; }
            else if (r == 1) { um = 0.125f*a0m + 0.875f*a1m; u0 = 0.125f*a00 + 0.875f*a10; up = 0.125f*a0p + 0.875f*a1p; }
            else if (r == 2) { um = 0.875f*a1m + 0.125f*a2m; u0 = 0.875f*a10 + 0.125f*a20; up = 0.875f*a1p + 0.125f*a2p; }
            else             { um = 0.625f*a1m + 0.375f*a2m; u0 = 0.625f*a10 + 0.375f*a20; up = 0.625f*a1p + 0.375f*a2p; }

            float pmv[4];
            pmv[0] = 0.375f * um + 0.625f * u0;
            pmv[1] = 0.125f * um + 0.875f * u0;
            pmv[2] = 0.875f * u0 + 0.125f * up;
            pmv[3] = 0.625f * u0 + 0.375f * up;

            f32x4 ov;
            #pragma unroll
            for (int j = 0; j < 4; ++j) {
                bool pos = pmv[j] > 0.0f;
                ov[j] = pos ? 1.0f : 0.0f;
                if (pos) { ssum += 1.0f / (1.0f + __expf(-pmv[j])); scnt++; }
            }
            __builtin_nontemporal_store(ov, (f32x4*)(dst + r * 800));
        }
    }

    // deterministic block reduction (fixed order), one atomic pair per block
    for (int off = 32; off > 0; off >>= 1) {
        ssum += __shfl_down(ssum, off);
        scnt += __shfl_down(scnt, off);
    }
    __shared__ float wsum[4];
    __shared__ int wcnt[4];
    const int wid = threadIdx.x >> 6;
    const int lane = threadIdx.x & 63;
    if (lane == 0) { wsum[wid] = ssum; wcnt[wid] = scnt; }
    __syncthreads();
    if (threadIdx.x == 0) {
        float tt = wsum[0] + wsum[1] + wsum[2] + wsum[3];
        int c = wcnt[0] + wcnt[1] + wcnt[2] + wcnt[3];
        if (c > 0) {
            // fixed-point 2^32 accumulate -> bit-deterministic across replays
            atomicAdd(&acc_sig[bq], (ull)((double)tt * 4294967296.0 + 0.5));
            atomicAdd(&acc_cnt[bq], (unsigned int)c);
        }
    }
}

// ---------------------------------------------------------------------------
// Kernel B-generic: fallback for pix != 640000 (unused for this problem).
// ---------------------------------------------------------------------------
__global__ __launch_bounds__(256) void mdh_masks_kernel(
    const float* __restrict__ mp,
    const int* __restrict__ ws_qidx,
    const int* __restrict__ hptr,
    const int* __restrict__ wptr,
    float* __restrict__ out_masks,
    ull* __restrict__ acc_sig,
    unsigned int* __restrict__ acc_cnt)
{
    const int bq = blockIdx.y;
    const int b = bq / KK;
    const int q = ws_qidx[bq];
    const int h = *hptr, w = *wptr;
    const long long pix = (long long)h * w;
    const float* __restrict__ src = mp + ((size_t)(b * QQ + q)) * (HM * WM);
    const float sy = (float)HM / (float)h;
    const float sx = (float)WM / (float)w;

    const long long p0 = (long long)blockIdx.x * 1024 + (long long)threadIdx.x * 4;
    float ssum = 0.0f;
    int scnt = 0;
    if (p0 < pix) {
        float pmv[4];
        for (int j = 0; j < 4; ++j) {
            long long p = p0 + j;
            if (p >= pix) { pmv[j] = -1.0f; continue; }
            int yy = (int)(p / w);
            int xx = (int)(p - (long long)yy * w);
            float yi = ((float)yy + 0.5f) * sy - 0.5f;
            float rf = floorf(yi); float fy = yi - rf;
            int r0 = max((int)rf, 0); int r1 = min((int)rf + 1, HM - 1);
            float xi = ((float)xx + 0.5f) * sx - 0.5f;
            float cf = floorf(xi); float fx = xi - cf;
            int c0 = max((int)cf, 0); int c1 = min((int)cf + 1, WM - 1);
            float a  = src[r0 * WM + c0], b2 = src[r0 * WM + c1];
            float c  = src[r1 * WM + c0], d2 = src[r1 * WM + c1];
            float t0 = (1.0f - fy) * a  + fy * c;
            float t1 = (1.0f - fy) * b2 + fy * d2;
            pmv[j] = (1.0f - fx) * t0 + fx * t1;
        }
        for (int j = 0; j < 4; ++j) {
            long long p = p0 + j;
            if (p >= pix) continue;
            bool pos = pmv[j] > 0.0f;
            out_masks[(size_t)bq * pix + p] = pos ? 1.0f : 0.0f;
            if (pos) { ssum += 1.0f / (1.0f + __expf(-pmv[j])); scnt++; }
        }
    }

    for (int off = 32; off > 0; off >>= 1) {
        ssum += __shfl_down(ssum, off);
        scnt += __shfl_down(scnt, off);
    }
    __shared__ float wsum[4];
    __shared__ int wcnt[4];
    const int wid = threadIdx.x >> 6;
    const int lane = threadIdx.x & 63;
    if (lane == 0) { wsum[wid] = ssum; wcnt[wid] = scnt; }
    __syncthreads();
    if (threadIdx.x == 0) {
        float tt = wsum[0] + wsum[1] + wsum[2] + wsum[3];
        int c = wcnt[0] + wcnt[1] + wcnt[2] + wcnt[3];
        if (c > 0) {
            atomicAdd(&acc_sig[bq], (ull)((double)tt * 4294967296.0 + 0.5));
            atomicAdd(&acc_cnt[bq], (unsigned int)c);
        }
    }
}

// ---------------------------------------------------------------------------
// Kernel C: obj = sig_sum / (count + 1e-6); pred_score; keep flags.
// ---------------------------------------------------------------------------
__global__ void mdh_final_kernel(
    const ull* __restrict__ acc_sig,
    const unsigned int* __restrict__ acc_cnt,
    const float* __restrict__ ws_val,
    const float* __restrict__ ws_area,
    float* __restrict__ out,
    long long pix)
{
    int t = blockIdx.x * blockDim.x + threadIdx.x;
    if (t < BB * KK) {
        float sig = (float)((double)acc_sig[t] * (1.0 / 4294967296.0));
        unsigned int cnt = acc_cnt[t];
        float obj = sig / ((float)cnt + 1e-6f);
        float ps = ws_val[t] * obj;
        out[(size_t)t * 5 + 4] = ps;
        bool keep = (cnt > 5) && (ws_area[t] > 10.0f) && (ps > 0.05f);
        out[(size_t)(BB * KK * 5 + BB * KK) + (size_t)BB * KK * pix + t] = keep ? 1.0f : 0.0f;
    }
}

extern "C" void kernel_launch(void* const* d_in, const int* in_sizes, int n_in,
                              void* d_out, int out_size, void* d_ws, size_t ws_size,
                              hipStream_t stream)
{
    const float* mp    = (const float*)d_in[0];   // (B,Q,200,200) f32
    const float* cls   = (const float*)d_in[1];   // (B,Q,80) f32
    const float* boxes = (const float*)d_in[2];   // (B,Q,4) f32
    const int* hptr    = (const int*)d_in[3];     // scalar h
    const int* wptr    = (const int*)d_in[4];     // scalar w
    float* out = (float*)d_out;

    // out layout: boxes_scores (B*K*5) | labels (B*K) | masks (B*K*h*w) | keep (B*K)
    const long long pix = ((long long)out_size - (long long)BB * KK * 7) / ((long long)BB * KK);

    char* wsb = (char*)d_ws;
    ull* acc_sig          = (ull*)wsb;                       // 200*8   @0
    unsigned int* acc_cnt = (unsigned int*)(wsb + 1600);     // 200*4   @1600
    float* ws_val         = (float*)(wsb + 2400);            // 200*4   @2400
    int* ws_qidx          = (int*)(wsb + 3200);              // 200*4   @3200
    float* ws_area        = (float*)(wsb + 4000);            // 200*4   @4000
    unsigned int* ws_keys = (unsigned int*)(wsb + 4800);     // 48000*4 @4800 (16B aligned)

    mdh_topk_kernel<<<BB, 1024, 0, stream>>>(cls, ws_keys, boxes, hptr, wptr, out,
                                             ws_val, ws_qidx, ws_area, acc_sig, acc_cnt);

    if (pix == 640000) {
        mdh_masks800_kernel<<<200 * 157, 256, 0, stream>>>(
            mp, ws_qidx, out + BB * KK * 6, acc_sig, acc_cnt);
    } else {
        const int nblk = (int)((pix + 1023) / 1024);
        mdh_masks_kernel<<<dim3(nblk, BB * KK), 256, 0, stream>>>(
            mp, ws_qidx, hptr, wptr, out + BB * KK * 6, acc_sig, acc_cnt);
    }

    mdh_final_kernel<<<1, 256, 0, stream>>>(acc_sig, acc_cnt, ws_val, ws_area, out, pix);
}